// Round 1
// baseline (254.147 us; speedup 1.0000x reference)
//
#include <hip/hip_runtime.h>

#define NCLS 1000
#define DIM 64
#define DG 4            // dim groups
#define DSUB 16         // dims per group (DG*DSUB == DIM)
#define CHUNKS 128      // row chunks
#define TPB 512

struct Ws {
    float    sums[NCLS * DIM];   // 256000 B
    int      counts[NCLS];       // 4000 B
    double   sumsq;              // offset 260000 (8-aligned)
    double   muterm;
    unsigned minkey;
    unsigned pad_;
    float    mu[NCLS * DIM];
    float    sq[NCLS];
};

__device__ __forceinline__ unsigned fkey(float x) {
    unsigned b = __float_as_uint(x);
    return (b & 0x80000000u) ? ~b : (b | 0x80000000u);
}
__device__ __forceinline__ float funkey(unsigned k) {
    return (k & 0x80000000u) ? __uint_as_float(k & 0x7FFFFFFFu)
                             : __uint_as_float(~k);
}

__global__ void k_init(Ws* ws) {
    if (threadIdx.x == 0) ws->minkey = fkey(1.0e24f);  // matches reference BIG fill
}

// Histogram of target -> counts
__global__ __launch_bounds__(256) void k_counts(const int* __restrict__ tgt, int n, Ws* ws) {
    __shared__ int cnt[NCLS];
    for (int i = threadIdx.x; i < NCLS; i += 256) cnt[i] = 0;
    __syncthreads();
    for (int r = blockIdx.x * 256 + threadIdx.x; r < n; r += gridDim.x * 256)
        atomicAdd(&cnt[tgt[r]], 1);
    __syncthreads();
    for (int i = threadIdx.x; i < NCLS; i += 256) {
        int c = cnt[i];
        if (c) atomicAdd(&ws->counts[i], c);
    }
}

// Main pass: per-class partial sums (dim-split in LDS) + total sum of squares
__global__ __launch_bounds__(TPB, 1) void k_accum(const float* __restrict__ emb,
                                                  const int* __restrict__ tgt,
                                                  int n, Ws* ws) {
    __shared__ float acc[NCLS * DSUB];   // 64000 B
    __shared__ float red[TPB / 64];
    const int bid   = blockIdx.x;
    const int g     = bid & (DG - 1);
    const int chunk = bid >> 2;
    const int tid   = threadIdx.x;

    for (int i = tid; i < NCLS * DSUB; i += TPB) acc[i] = 0.f;
    __syncthreads();

    const int rows_per_chunk = (n + CHUNKS - 1) / CHUNKS;
    const int r0 = chunk * rows_per_chunk;
    const int r1 = min(n, r0 + rows_per_chunk);
    const int lane4 = tid & 3;

    float ssq = 0.f;
    for (int r = r0 + (tid >> 2); r < r1; r += TPB / 4) {
        const int t = tgt[r];
        const float4 v = *reinterpret_cast<const float4*>(
            emb + (size_t)r * DIM + g * DSUB + lane4 * 4);
        ssq += v.x * v.x + v.y * v.y + v.z * v.z + v.w * v.w;
        float* a = &acc[t * DSUB + lane4 * 4];
        atomicAdd(a + 0, v.x);
        atomicAdd(a + 1, v.y);
        atomicAdd(a + 2, v.z);
        atomicAdd(a + 3, v.w);
    }
    __syncthreads();

    // flush partial sums to global (coalesced per class segment)
    for (int i = tid; i < NCLS * DSUB; i += TPB) {
        float vsum = acc[i];
        if (vsum != 0.f) {
            int c = i / DSUB, d = i - c * DSUB;
            atomicAdd(&ws->sums[c * DIM + g * DSUB + d], vsum);
        }
    }

    // block-reduce sum of squares -> one double atomic per block
    for (int off = 32; off; off >>= 1) ssq += __shfl_down(ssq, off);
    if ((tid & 63) == 0) red[tid >> 6] = ssq;
    __syncthreads();
    if (tid == 0) {
        float s = 0.f;
        #pragma unroll
        for (int w = 0; w < TPB / 64; ++w) s += red[w];
        atomicAdd(&ws->sumsq, (double)s);
    }
}

// mu = sums / max(counts,1); sq[c] = ||mu_c||^2; muterm += counts_c * sq[c]
__global__ __launch_bounds__(64) void k_centers(Ws* ws) {
    const int c = blockIdx.x;
    const int d = threadIdx.x;
    const int cv = ws->counts[c];
    const float m = ws->sums[c * DIM + d] / (float)max(cv, 1);
    ws->mu[c * DIM + d] = m;
    float p = m * m;
    for (int off = 32; off; off >>= 1) p += __shfl_down(p, off);
    if (d == 0) {
        ws->sq[c] = p;
        if (cv) atomicAdd(&ws->muterm, (double)((float)cv * p));
    }
}

// pairwise squared distances among present centers; global min via keyed atomicMin
__global__ __launch_bounds__(256) void k_pairs(Ws* ws) {
    __shared__ float mua[DIM];
    __shared__ unsigned redm[4];
    const int a = blockIdx.x;
    const int tid = threadIdx.x;
    if (ws->counts[a] == 0) return;  // uniform across block
    if (tid < DIM) mua[tid] = ws->mu[a * DIM + tid];
    __syncthreads();
    const float sqa = ws->sq[a];
    float best = 3.0e38f;
    for (int b = tid; b < NCLS; b += 256) {
        if (b == a || ws->counts[b] == 0) continue;
        const float* __restrict__ mb = &ws->mu[b * DIM];
        float dot = 0.f;
        #pragma unroll
        for (int k = 0; k < DIM; ++k) dot += mua[k] * mb[k];
        float dist = sqa + ws->sq[b] - 2.f * dot;
        best = fminf(best, dist);
    }
    for (int off = 32; off; off >>= 1) best = fminf(best, __shfl_down(best, off));
    if ((tid & 63) == 0) redm[tid >> 6] = fkey(best);
    __syncthreads();
    if (tid == 0) {
        unsigned m = redm[0];
        #pragma unroll
        for (int w = 1; w < 4; ++w) m = min(m, redm[w]);
        atomicMin(&ws->minkey, m);
    }
}

__global__ void k_final(const Ws* ws, float* out, int n) {
    if (threadIdx.x == 0) {
        out[0] = (float)((ws->sumsq - ws->muterm) / (double)n);
        out[1] = -funkey(ws->minkey);
    }
}

extern "C" void kernel_launch(void* const* d_in, const int* in_sizes, int n_in,
                              void* d_out, int out_size, void* d_ws, size_t ws_size,
                              hipStream_t stream) {
    const float* emb = (const float*)d_in[0];
    const int*   tgt = (const int*)d_in[1];
    float* out = (float*)d_out;
    const int n = in_sizes[1];        // 400000 rows
    Ws* ws = (Ws*)d_ws;

    // zero sums/counts/sumsq/muterm (everything before minkey), then set minkey
    size_t zbytes = offsetof(Ws, minkey);
    hipMemsetAsync(d_ws, 0, zbytes, stream);
    k_init<<<1, 64, 0, stream>>>(ws);

    k_counts<<<128, 256, 0, stream>>>(tgt, n, ws);
    k_accum<<<DG * CHUNKS, TPB, 0, stream>>>(emb, tgt, n, ws);
    k_centers<<<NCLS, 64, 0, stream>>>(ws);
    k_pairs<<<NCLS, 256, 0, stream>>>(ws);
    k_final<<<1, 64, 0, stream>>>(ws, out, n);
}

// Round 2
// 176.444 us; speedup vs baseline: 1.4404x; 1.4404x over previous
//
#include <hip/hip_runtime.h>

#define NCLS 1000
#define DIM 64
#define DG 8            // dim groups
#define DSUB 8          // dims per group (DG*DSUB == DIM)
#define CHUNKS 64       // row chunks
#define TPB 512
#define RSTEP (TPB / 2) // rows per block per half-iteration

struct Ws {
    float    sums[NCLS * DIM];   // 256000 B
    int      counts[NCLS];       // 4000 B
    double   sumsq;              // 8-aligned
    double   muterm;
    unsigned minkey;
    unsigned pad_;
    float    mu[NCLS * DIM];
    float    sq[NCLS];
};

__device__ __forceinline__ unsigned fkey(float x) {
    unsigned b = __float_as_uint(x);
    return (b & 0x80000000u) ? ~b : (b | 0x80000000u);
}
__device__ __forceinline__ float funkey(unsigned k) {
    return (k & 0x80000000u) ? __uint_as_float(k & 0x7FFFFFFFu)
                             : __uint_as_float(~k);
}

// Main pass: per-class partial sums (dim-split in LDS) + counts (g==0 blocks)
// + total sum of squares.
__global__ __launch_bounds__(TPB, 8) void k_accum(const float* __restrict__ emb,
                                                  const int* __restrict__ tgt,
                                                  int n, Ws* ws) {
    __shared__ float acc[NCLS * DSUB];   // 32000 B
    __shared__ int   cnt[NCLS];          //  4000 B
    __shared__ float red[TPB / 64];

    const int bid   = blockIdx.x;
    const int chunk = bid & (CHUNKS - 1);   // same-chunk blocks land on same XCD
    const int g     = bid >> 6;             // dim group 0..7
    const int tid   = threadIdx.x;
    const bool do_cnt = (g == 0);

    for (int i = tid; i < NCLS * DSUB; i += TPB) acc[i] = 0.f;
    if (do_cnt) for (int i = tid; i < NCLS; i += TPB) cnt[i] = 0;
    __syncthreads();

    const int rows_per_chunk = (n + CHUNKS - 1) / CHUNKS;
    const int r0 = chunk * rows_per_chunk;
    const int r1 = min(n, r0 + rows_per_chunk);
    const int half  = tid >> 1;       // 0..255
    const int lane2 = tid & 1;
    const int coff  = g * DSUB + lane2 * 4;

    float ssq = 0.f;
    for (int rb = r0; rb < r1; rb += 2 * RSTEP) {
        const int ra = rb + half;
        const int rc = ra + RSTEP;
        const bool p0 = ra < r1;
        const bool p1 = rc < r1;
        int t0 = 0, t1 = 0;
        float4 v0 = make_float4(0.f, 0.f, 0.f, 0.f);
        float4 v1 = make_float4(0.f, 0.f, 0.f, 0.f);
        if (p0) {
            t0 = tgt[ra];
            v0 = *reinterpret_cast<const float4*>(emb + (size_t)ra * DIM + coff);
        }
        if (p1) {
            t1 = tgt[rc];
            v1 = *reinterpret_cast<const float4*>(emb + (size_t)rc * DIM + coff);
        }
        ssq += v0.x * v0.x + v0.y * v0.y + v0.z * v0.z + v0.w * v0.w
             + v1.x * v1.x + v1.y * v1.y + v1.z * v1.z + v1.w * v1.w;
        if (p0) {
            float* a = &acc[t0 * DSUB + lane2 * 4];
            atomicAdd(a + 0, v0.x); atomicAdd(a + 1, v0.y);
            atomicAdd(a + 2, v0.z); atomicAdd(a + 3, v0.w);
            if (do_cnt && lane2 == 0) atomicAdd(&cnt[t0], 1);
        }
        if (p1) {
            float* a = &acc[t1 * DSUB + lane2 * 4];
            atomicAdd(a + 0, v1.x); atomicAdd(a + 1, v1.y);
            atomicAdd(a + 2, v1.z); atomicAdd(a + 3, v1.w);
            if (do_cnt && lane2 == 0) atomicAdd(&cnt[t1], 1);
        }
    }
    __syncthreads();

    // flush partial sums to global (coalesced per class segment)
    for (int i = tid; i < NCLS * DSUB; i += TPB) {
        float vsum = acc[i];
        if (vsum != 0.f) {
            int c = i / DSUB, d = i - c * DSUB;
            atomicAdd(&ws->sums[c * DIM + g * DSUB + d], vsum);
        }
    }
    if (do_cnt) {
        for (int i = tid; i < NCLS; i += TPB) {
            int c = cnt[i];
            if (c) atomicAdd(&ws->counts[i], c);
        }
    }

    // block-reduce sum of squares -> one double atomic per block
    for (int off = 32; off; off >>= 1) ssq += __shfl_down(ssq, off);
    if ((tid & 63) == 0) red[tid >> 6] = ssq;
    __syncthreads();
    if (tid == 0) {
        float s = 0.f;
        #pragma unroll
        for (int w = 0; w < TPB / 64; ++w) s += red[w];
        atomicAdd(&ws->sumsq, (double)s);
    }
}

// mu = sums / max(counts,1); sq[c] = ||mu_c||^2; muterm += counts_c * sq[c]
// block 0 thread 0 also initializes minkey (saves a launch).
__global__ __launch_bounds__(64) void k_centers(Ws* ws) {
    const int c = blockIdx.x;
    const int d = threadIdx.x;
    if (c == 0 && d == 0) ws->minkey = fkey(1.0e24f);  // matches reference BIG fill
    const int cv = ws->counts[c];
    const float m = ws->sums[c * DIM + d] / (float)max(cv, 1);
    ws->mu[c * DIM + d] = m;
    float p = m * m;
    for (int off = 32; off; off >>= 1) p += __shfl_down(p, off);
    if (d == 0) {
        ws->sq[c] = p;
        if (cv) atomicAdd(&ws->muterm, (double)((float)cv * p));
    }
}

// Tiled pairwise-min: 16x16 upper-triangular 64x64 tiles, 4x4 micro-tile/thread.
#define TILE 64
#define NTA 16                       // ceil(1000/64)
#define NPAIR (NTA * (NTA + 1) / 2)  // 136
__global__ __launch_bounds__(256) void k_pairs(Ws* ws) {
    __shared__ float As[TILE][DIM + 4];   // +4: 16B-aligned, 2-way max on reads
    __shared__ float Bst[DIM][TILE + 1];  // transposed B, 2-way max
    __shared__ float sqa_s[TILE], sqb_s[TILE];
    __shared__ int   pa_s[TILE], pb_s[TILE];
    __shared__ unsigned redm[4];

    // decode upper-triangle tile pair (ta <= tb)
    int rem = blockIdx.x, ta = 0;
    while (rem >= NTA - ta) { rem -= NTA - ta; ++ta; }
    const int tb = ta + rem;
    const int tid = threadIdx.x;

    for (int i = tid; i < TILE * (DIM / 4); i += 256) {
        const int r = i >> 4, c4 = (i & 15) * 4;
        const int ga = ta * TILE + r;
        const int gb = tb * TILE + r;
        float4 va = make_float4(0.f, 0.f, 0.f, 0.f);
        float4 vb = make_float4(0.f, 0.f, 0.f, 0.f);
        if (ga < NCLS) va = *reinterpret_cast<const float4*>(&ws->mu[ga * DIM + c4]);
        if (gb < NCLS) vb = *reinterpret_cast<const float4*>(&ws->mu[gb * DIM + c4]);
        *reinterpret_cast<float4*>(&As[r][c4]) = va;
        Bst[c4 + 0][r] = vb.x; Bst[c4 + 1][r] = vb.y;
        Bst[c4 + 2][r] = vb.z; Bst[c4 + 3][r] = vb.w;
    }
    if (tid < TILE) {
        const int ga = ta * TILE + tid;
        const int gb = tb * TILE + tid;
        pa_s[tid]  = (ga < NCLS) ? (ws->counts[ga] > 0) : 0;
        sqa_s[tid] = (ga < NCLS) ? ws->sq[ga] : 0.f;
        pb_s[tid]  = (gb < NCLS) ? (ws->counts[gb] > 0) : 0;
        sqb_s[tid] = (gb < NCLS) ? ws->sq[gb] : 0.f;
    }
    __syncthreads();

    const int ty4 = (tid >> 4) * 4;
    const int tx4 = (tid & 15) * 4;
    float dot[4][4];
    #pragma unroll
    for (int i = 0; i < 4; ++i)
        #pragma unroll
        for (int j = 0; j < 4; ++j) dot[i][j] = 0.f;

    #pragma unroll 8
    for (int k = 0; k < DIM; ++k) {
        float av[4], bv[4];
        #pragma unroll
        for (int i = 0; i < 4; ++i) av[i] = As[ty4 + i][k];
        #pragma unroll
        for (int j = 0; j < 4; ++j) bv[j] = Bst[k][tx4 + j];
        #pragma unroll
        for (int i = 0; i < 4; ++i)
            #pragma unroll
            for (int j = 0; j < 4; ++j) dot[i][j] += av[i] * bv[j];
    }

    float best = 3.0e38f;
    #pragma unroll
    for (int i = 0; i < 4; ++i) {
        #pragma unroll
        for (int j = 0; j < 4; ++j) {
            const int ga = ta * TILE + ty4 + i;
            const int gb = tb * TILE + tx4 + j;
            const bool valid = pa_s[ty4 + i] && pb_s[tx4 + j] && (ga != gb);
            const float dd = sqa_s[ty4 + i] + sqb_s[tx4 + j] - 2.f * dot[i][j];
            if (valid) best = fminf(best, dd);
        }
    }
    for (int off = 32; off; off >>= 1) best = fminf(best, __shfl_down(best, off));
    if ((tid & 63) == 0) redm[tid >> 6] = fkey(best);
    __syncthreads();
    if (tid == 0) {
        unsigned m = redm[0];
        #pragma unroll
        for (int w = 1; w < 4; ++w) m = min(m, redm[w]);
        atomicMin(&ws->minkey, m);
    }
}

__global__ void k_final(const Ws* ws, float* out, int n) {
    if (threadIdx.x == 0) {
        out[0] = (float)((ws->sumsq - ws->muterm) / (double)n);
        out[1] = -funkey(ws->minkey);
    }
}

extern "C" void kernel_launch(void* const* d_in, const int* in_sizes, int n_in,
                              void* d_out, int out_size, void* d_ws, size_t ws_size,
                              hipStream_t stream) {
    const float* emb = (const float*)d_in[0];
    const int*   tgt = (const int*)d_in[1];
    float* out = (float*)d_out;
    const int n = in_sizes[1];        // 400000 rows
    Ws* ws = (Ws*)d_ws;

    // zero sums/counts/sumsq/muterm; minkey is set inside k_centers
    hipMemsetAsync(d_ws, 0, offsetof(Ws, minkey), stream);
    k_accum<<<DG * CHUNKS, TPB, 0, stream>>>(emb, tgt, n, ws);
    k_centers<<<NCLS, 64, 0, stream>>>(ws);
    k_pairs<<<NPAIR, 256, 0, stream>>>(ws);
    k_final<<<1, 64, 0, stream>>>(ws, out, n);
}